// Round 7
// baseline (125.926 us; speedup 1.0000x reference)
//
#include <hip/hip_runtime.h>

// QueryAndGroup: ball_query(r=0.2, ns=32) + group xyz (centered) + group features.
//   xyz      [8][16384][3] f32   d_in[0]
//   new_xyz  [8][1024][3]  f32   d_in[1]
//   features [8][64][16384] f32  d_in[2]
//   out      [8][67][1024][32] f32
//
// R6 evidence: SoA cut qg_main 48->~30us (TA line-request theory confirmed).
// R7: (1) overlap the BW-bound feature transpose with the latency-bound ball
// query in one fat kernel (8-block type interleave, b=blockIdx&7 kept for both
// so each XCD's L2 holds its batch's 4MB ft slab); query writes centered
// coords+idx meta to ws. (2) dense group kernel: pure gather+store, no
// stragglers. (3) scan 256 pts/iter via float4 SoA loads (12 lines/iter),
// rank via 4 ballots + intra-lane prefix.

#define N_PTS   16384
#define M_Q     1024
#define B_SZ    8
#define NSAMP   32
#define NCH     64
#define R2      0.04f
#define OUT_CH  (3 + NCH)

typedef float f4 __attribute__((ext_vector_type(4)));

// ---------- K0: xyz AoS -> SoA (1.5 MB, ~2us) ----------
__global__ __launch_bounds__(256) void soa_kernel(
    const float* __restrict__ xyz,
    float* __restrict__ xs, float* __restrict__ ys, float* __restrict__ zs)
{
    const int i = blockIdx.x * 256 + threadIdx.x;       // 0..131071 = B*N
    const float* src = xyz + (size_t)i * 3;
    xs[i] = src[0];
    ys[i] = src[1];
    zs[i] = src[2];
}

// ---------- K1 fat: transpose tiles (type 0) || ball query (type 1) ----------
// 4096 blocks: type = (blockIdx>>3)&1, u = (blockIdx&7) | ((blockIdx>>4)<<3).
// Both paths: batch b = u&7 -> XCD b (blocks dispatched round-robin mod 8).
__global__ __launch_bounds__(256) void fat_kernel(
    const float* __restrict__ feat,     // [B][C][N]
    const float* __restrict__ new_xyz,  // [B][M][3]
    const float* __restrict__ xs, const float* __restrict__ ys,
    const float* __restrict__ zs,
    float* __restrict__ ft,             // [B][N][C]
    f4* __restrict__ meta)              // [B*M][NSAMP] = {dxc,dyc,dzc,bits(idx)}
{
    __shared__ float tile[64][65];                  // transpose path
    __shared__ float pxyz[4][NSAMP][4];             // query path
    const int tid  = threadIdx.x;
    const int u    = (blockIdx.x & 7) | ((blockIdx.x >> 4) << 3);   // 0..2047
    const int type = (blockIdx.x >> 3) & 1;
    const int b    = u & 7;

    if (type == 0) {
        // ---- transpose tile: feat[b][:, n0:n0+64] -> ft[b][n0:n0+64][:] ----
        const int n0 = (u >> 3) << 6;
        const float* __restrict__ fb = feat + (size_t)b * NCH * N_PTS;
        float* __restrict__ tb       = ft   + ((size_t)b * N_PTS + n0) * NCH;
#pragma unroll
        for (int j = 0; j < 16; ++j) {              // read coalesced along n
            const int idx = j * 256 + tid;
            const int c = idx >> 6, nn = idx & 63;
            tile[c][nn] = __builtin_nontemporal_load(&fb[(size_t)c * N_PTS + n0 + nn]);
        }
        __syncthreads();
        const int c4 = tid & 15;
        const int r  = tid >> 4;
#pragma unroll
        for (int j = 0; j < 4; ++j) {               // write 1KB dwordx4 per instr
            const int nn = j * 16 + r;
            f4 o;
            o.x = tile[c4 * 4 + 0][nn];
            o.y = tile[c4 * 4 + 1][nn];
            o.z = tile[c4 * 4 + 2][nn];
            o.w = tile[c4 * 4 + 3][nn];
            *(f4*)(&tb[(size_t)nn * NCH + c4 * 4]) = o;   // re-read by K2: keep cached
        }
        return;
    }

    // ---- query path: 4 waves, one query each; NO __syncthreads ----
    const int w    = tid >> 6;
    const int lane = tid & 63;
    const int m    = ((u >> 3) << 2) + w;
    const int q    = (b << 10) + m;

    const float cx = new_xyz[q * 3 + 0];
    const float cy = new_xyz[q * 3 + 1];
    const float cz = new_xyz[q * 3 + 2];
    const float* __restrict__ xsb = xs + (size_t)b * N_PTS;
    const float* __restrict__ ysb = ys + (size_t)b * N_PTS;
    const float* __restrict__ zsb = zs + (size_t)b * N_PTS;

    const unsigned long long lt = (1ull << lane) - 1ull;
    int cnt = 0;
    // 256 points/iter: lane holds points p0..p0+3 (order = base + 4*lane + j, l-major)
    for (int base = 0; base < N_PTS; base += 256) {
        const int p0 = base + 4 * lane;
        const f4 X = *(const f4*)(xsb + p0);
        const f4 Y = *(const f4*)(ysb + p0);
        const f4 Z = *(const f4*)(zsb + p0);
        float dxs[4], dys[4], dzs[4];
        unsigned long long bl[4];
        bool hits[4];
#pragma unroll
        for (int j = 0; j < 4; ++j) {
            const float dx = __fsub_rn(cx, X[j]);
            const float dy = __fsub_rn(cy, Y[j]);
            const float dz = __fsub_rn(cz, Z[j]);
            const float d2 = __fadd_rn(__fadd_rn(__fmul_rn(dx, dx), __fmul_rn(dy, dy)),
                                       __fmul_rn(dz, dz));
            dxs[j] = dx; dys[j] = dy; dzs[j] = dz;
            hits[j] = d2 < R2;
            bl[j]   = __ballot(hits[j]);
        }
        // rank(l,j) = sum_j' popc(bl[j'] & lanes<l) + #{j'<j hit at own lane}
        const int pre = __popcll(bl[0] & lt) + __popcll(bl[1] & lt)
                      + __popcll(bl[2] & lt) + __popcll(bl[3] & lt);
        int own = 0;
#pragma unroll
        for (int j = 0; j < 4; ++j) {
            if (hits[j]) {
                const int slot = cnt + pre + own;
                if (slot < NSAMP) {
                    pxyz[w][slot][0] = -dxs[j];     // = X[j]-cx (exact negation)
                    pxyz[w][slot][1] = -dys[j];
                    pxyz[w][slot][2] = -dzs[j];
                    pxyz[w][slot][3] = __int_as_float(p0 + j);
                }
            }
            own += (int)((bl[j] >> lane) & 1ull);
        }
        cnt += __popcll(bl[0]) + __popcll(bl[1]) + __popcll(bl[2]) + __popcll(bl[3]);
        if (cnt >= NSAMP) break;
    }

    // fill empty slots with slot 0 (reference broadcasts sorted_idx[...,0])
    if (lane < NSAMP && cnt < NSAMP) {
        float v0x, v0y, v0z, v0w;
        if (cnt > 0) {
            v0x = pxyz[w][0][0]; v0y = pxyz[w][0][1];
            v0z = pxyz[w][0][2]; v0w = pxyz[w][0][3];
        } else {
            v0x = __fsub_rn(xsb[0], cx); v0y = __fsub_rn(ysb[0], cy);
            v0z = __fsub_rn(zsb[0], cz); v0w = __int_as_float(0);
        }
        if (lane >= cnt) {
            pxyz[w][lane][0] = v0x; pxyz[w][lane][1] = v0y;
            pxyz[w][lane][2] = v0z; pxyz[w][lane][3] = v0w;
        }
    }
    // wave-synchronous LDS: same-wave ds_write -> ds_read ordered by lgkmcnt
    if (lane < NSAMP) {
        f4 mv;
        mv.x = pxyz[w][lane][0];
        mv.y = pxyz[w][lane][1];
        mv.z = pxyz[w][lane][2];
        mv.w = pxyz[w][lane][3];
        meta[(size_t)q * NSAMP + lane] = mv;
    }
}

// ---------- K2: dense group/gather. No stragglers, stores stream. ----------
__global__ __launch_bounds__(256) void group_kernel(
    const f4* __restrict__ meta,        // [B*M][NSAMP]
    const float* __restrict__ ft,       // [B][N][C]
    float* __restrict__ out)            // [B][67][M][NS]
{
    const int tid  = threadIdx.x;
    const int w    = tid >> 6;
    const int lane = tid & 63;
    const int b    = blockIdx.x & 7;                // XCD swizzle matches K1
    const int m    = ((blockIdx.x >> 3) << 2) + w;
    const int q    = (b << 10) + m;

    __shared__ float pxyz[4][NSAMP][4];
    __shared__ float tile[4][32][33];

    if (lane < NSAMP) {
        const f4 mv = meta[(size_t)q * NSAMP + lane];
        pxyz[w][lane][0] = mv.x;
        pxyz[w][lane][1] = mv.y;
        pxyz[w][lane][2] = mv.z;
        pxyz[w][lane][3] = mv.w;
    }

    float* __restrict__ ob = out + ((size_t)b * OUT_CH * M_Q + (size_t)m) * NSAMP;

    // xyz channels: already centered in meta, straight copy (1 dwordx4 x 24 lanes)
    if (lane < 24) {
        const int c  = lane >> 3;        // 0..2
        const int s4 = lane & 7;
        f4 o;
        o.x = pxyz[w][s4 * 4 + 0][c];
        o.y = pxyz[w][s4 * 4 + 1][c];
        o.z = pxyz[w][s4 * 4 + 2][c];
        o.w = pxyz[w][s4 * 4 + 3][c];
        __builtin_nontemporal_store(o, (f4*)&ob[(size_t)c * (M_Q * NSAMP) + s4 * 4]);
    }

    // feature rows (256B contiguous in ft), LDS transpose, dwordx4 nt stores
    const float* __restrict__ ftb = ft + (size_t)b * N_PTS * NCH;
    const int sgrp = lane >> 3;          // 0..7
    const int c4   = lane & 7;

#pragma unroll
    for (int chunk = 0; chunk < 2; ++chunk) {
        f4 vals[4];
#pragma unroll
        for (int i = 0; i < 4; ++i) {    // 8 lanes x 128B per row-half
            const int s = i * 8 + sgrp;
            const int n = __float_as_int(pxyz[w][s][3]);
            vals[i] = *(const f4*)(ftb + (size_t)n * NCH + chunk * 32 + c4 * 4);
        }
#pragma unroll
        for (int i = 0; i < 4; ++i) {    // [s][c] -> [c][s]
            const int s = i * 8 + sgrp;
            tile[w][c4 * 4 + 0][s] = vals[i].x;
            tile[w][c4 * 4 + 1][s] = vals[i].y;
            tile[w][c4 * 4 + 2][s] = vals[i].z;
            tile[w][c4 * 4 + 3][s] = vals[i].w;
        }
#pragma unroll
        for (int j = 0; j < 4; ++j) {    // 1KB nt store per instr
            const int c_loc = j * 8 + (lane >> 3);
            const int s4    = lane & 7;
            f4 o;
            o.x = tile[w][c_loc][s4 * 4 + 0];
            o.y = tile[w][c_loc][s4 * 4 + 1];
            o.z = tile[w][c_loc][s4 * 4 + 2];
            o.w = tile[w][c_loc][s4 * 4 + 3];
            __builtin_nontemporal_store(
                o, (f4*)&ob[(size_t)(3 + chunk * 32 + c_loc) * (M_Q * NSAMP) + s4 * 4]);
        }
    }
}

// ---------- fallback (ws too small): direct-gather kernel ----------
__global__ __launch_bounds__(256) void qg_fallback(
    const float* __restrict__ xyz, const float* __restrict__ new_xyz,
    const float* __restrict__ feat, float* __restrict__ out)
{
    const int tid  = threadIdx.x;
    const int w    = tid >> 6;
    const int lane = tid & 63;
    const int q    = blockIdx.x * 4 + w;
    const int b    = q >> 10;
    const int m    = q & (M_Q - 1);

    __shared__ int idx_sh[4][NSAMP];

    const float cx = new_xyz[q * 3 + 0];
    const float cy = new_xyz[q * 3 + 1];
    const float cz = new_xyz[q * 3 + 2];
    const float* __restrict__ xb = xyz + (size_t)b * N_PTS * 3;

    int cnt = 0;
    for (int base = 0; base < N_PTS && cnt < NSAMP; base += 64) {
        const int n = base + lane;
        const float dx = __fsub_rn(cx, xb[n * 3 + 0]);
        const float dy = __fsub_rn(cy, xb[n * 3 + 1]);
        const float dz = __fsub_rn(cz, xb[n * 3 + 2]);
        const float d2 = __fadd_rn(__fadd_rn(__fmul_rn(dx, dx), __fmul_rn(dy, dy)),
                                   __fmul_rn(dz, dz));
        const bool hit = d2 < R2;
        const unsigned long long mk = __ballot(hit);
        if (hit) {
            const int slot = cnt + __popcll(mk & ((1ull << lane) - 1ull));
            if (slot < NSAMP) idx_sh[w][slot] = n;
        }
        cnt += (int)__popcll(mk);
    }
    __syncthreads();
    if (lane < NSAMP) {
        const int v0 = (cnt > 0) ? idx_sh[w][0] : 0;
        if (lane >= cnt) idx_sh[w][lane] = v0;
    }
    __syncthreads();

    const float* __restrict__ fb = feat + (size_t)b * NCH * N_PTS;
    float* __restrict__ ob = out + ((size_t)b * OUT_CH * M_Q + (size_t)m) * NSAMP;
    for (int e = lane; e < OUT_CH * NSAMP; e += 64) {
        const int c = e >> 5, s = e & 31;
        const int n = idx_sh[w][s];
        float v;
        if (c < 3) {
            const float ctr = (c == 0) ? cx : ((c == 1) ? cy : cz);
            v = __fsub_rn(xb[n * 3 + c], ctr);
        } else {
            v = fb[(size_t)(c - 3) * N_PTS + n];
        }
        ob[(size_t)c * (M_Q * NSAMP) + s] = v;
    }
}

extern "C" void kernel_launch(void* const* d_in, const int* in_sizes, int n_in,
                              void* d_out, int out_size, void* d_ws, size_t ws_size,
                              hipStream_t stream) {
    const float* xyz     = (const float*)d_in[0];
    const float* new_xyz = (const float*)d_in[1];
    const float* feat    = (const float*)d_in[2];
    float* out           = (float*)d_out;

    const size_t ft_elems   = (size_t)B_SZ * N_PTS * NCH;       // 8388608
    const size_t soa_elems  = (size_t)B_SZ * N_PTS;             // 131072
    const size_t meta_elems = (size_t)B_SZ * M_Q * NSAMP * 4;   // 1048576
    const size_t need = (ft_elems + 3 * soa_elems + meta_elems) * sizeof(float); // ~39.3MB

    float* ft   = (float*)d_ws;
    float* xs   = ft + ft_elems;
    float* ys   = xs + soa_elems;
    float* zs   = ys + soa_elems;
    f4*    meta = (f4*)(zs + soa_elems);

    if (ws_size >= need) {
        soa_kernel<<<(B_SZ * N_PTS) / 256, 256, 0, stream>>>(xyz, xs, ys, zs);
        fat_kernel<<<4096, 256, 0, stream>>>(feat, new_xyz, xs, ys, zs, ft, meta);
        group_kernel<<<(B_SZ * M_Q) / 4, 256, 0, stream>>>(meta, ft, out);
    } else {
        qg_fallback<<<(B_SZ * M_Q) / 4, 256, 0, stream>>>(xyz, new_xyz, feat, out);
    }
}